// Round 17
// baseline (2584.940 us; speedup 1.0000x reference)
//
#include <hip/hip_runtime.h>
#include <math.h>

#define TSEQ 512
#define HDIM 512
#define EDIM 512
#define NB   32
#define ROWS 64
#define GATES 2048
#define NEGV -1000000000.0f

typedef __attribute__((ext_vector_type(8))) short bf16x8;
typedef __attribute__((ext_vector_type(4))) float f32x4;

__device__ __forceinline__ float sigf(float x){ return __builtin_amdgcn_rcpf(1.0f + __expf(-x)); }

__device__ __forceinline__ float tanhfast(float x){
  float t = __expf(-2.0f*fabsf(x));
  float r = (1.0f - t)*__builtin_amdgcn_rcpf(1.0f + t);
  return copysignf(r, x);
}

__device__ __forceinline__ unsigned short f2bf(float f){
  unsigned int u = __builtin_bit_cast(unsigned int, f);
  unsigned int r = (u + 0x7fff + ((u>>16)&1)) >> 16;
  return (unsigned short)r;
}

__device__ __forceinline__ float bf2f(unsigned short v){
  unsigned int u = ((unsigned int)v)<<16;
  return __builtin_bit_cast(float, u);
}

// table[v][j] = sum_k emb[v][k] * W_ih[k][j] + b_lstm[j]   (fp32)
__global__ __launch_bounds__(256) void table_k(const float* __restrict__ emb,
        const float* __restrict__ W_ih, const float* __restrict__ b_lstm,
        float* __restrict__ table){
  int j = blockIdx.x*256 + threadIdx.x;
  int v = blockIdx.y;
  float acc = b_lstm[j];
  #pragma unroll 4
  for(int k=0;k<EDIM;k++) acc = fmaf(emb[v*EDIM+k], W_ih[(size_t)k*GATES+j], acc);
  table[(size_t)v*GATES+j] = acc;
}

// W_hh -> bf16 B-fragment order. cid = js*64 + g*16 + kc.
__global__ __launch_bounds__(64) void wprep_k(const float* __restrict__ W_hh,
        unsigned short* __restrict__ Wswz){
  int cid = blockIdx.x;           // 0..2047
  int lane = threadIdx.x;
  int js = cid>>6, g = (cid>>4)&3, kc = cid&15;
  int col = g*512 + js*16 + (lane&15);
  int kbase = kc*32 + (lane>>4)*8;
  unsigned short v[8];
  #pragma unroll
  for(int e=0;e<8;e++) v[e] = f2bf(W_hh[(size_t)(kbase+e)*GATES + col]);
  *(uint4*)&Wswz[((size_t)cid*64 + lane)*8] = *(const uint4*)v;
}

// W_out -> bf16 B-fragment order. cid = nc*16 + kc.
__global__ __launch_bounds__(64) void wprep2_k(const float* __restrict__ W_out,
        unsigned short* __restrict__ wsw){
  int cid = blockIdx.x;           // 0..511
  int lane = threadIdx.x;
  int nc = cid>>4, kc = cid&15;
  int col = nc*16 + (lane&15);
  int kb = kc*32 + (lane>>4)*8;
  unsigned short v[8];
  #pragma unroll
  for(int e=0;e<8;e++) v[e] = f2bf(W_out[(size_t)(kb+e)*EDIM + col]);
  *(uint4*)&wsw[((size_t)cid*64 + lane)*8] = *(const uint4*)v;
}

// Persistent LSTM (R14-proven): 128 single-wave WGs. W gates 0-2 in 192 VGPRs,
// gate 3 in 16KB LDS. Tagged-dword h exchange.
// Two-phase wait: 4B/lane sentinel spin, then ONE validated full pass.
__global__ __launch_bounds__(64,1) void lstm_wave(const int* __restrict__ x, const int* __restrict__ y,
        const float* __restrict__ table, const unsigned short* __restrict__ Wswz,
        unsigned* __restrict__ hx, unsigned short* __restrict__ hsb){
  __shared__ unsigned short wlds[8192];   // 16KB: gate 3 [kc][lane][8]
  int w = blockIdx.x;            // 0..127
  int c = w>>6, mh = (w>>5)&1, js = w&31;
  int gid = c*2 + mh;
  int lane = threadIdx.x;

  // gates 0..2 -> registers (48 x bf16x8 = 192 VGPRs)
  bf16x8 wf[48];
  {
    const unsigned short* wp = Wswz + (size_t)js*32768;
    #pragma unroll
    for(int g=0;g<3;g++)
      #pragma unroll
      for(int kc=0;kc<16;kc++)
        wf[g*16+kc] = *(const bf16x8*)(const void*)&wp[((size_t)(g*16+kc)*64 + lane)*8];
  }
  { // gate 3 -> LDS (contiguous 16KB)
    const uint4* src = (const uint4*)(Wswz + (size_t)js*32768 + 48*512);
    uint4* dst = (uint4*)wlds;
    #pragma unroll
    for(int i=0;i<16;i++) dst[lane + i*64] = src[lane + i*64];
  }
  __syncthreads();

  const int* tokbase = c ? y : x;
  int jloc = lane&15;
  int j    = js*16 + jloc;
  int hi   = (j>>3)&3;
  int kc_o = j>>5;
  int e_o  = j&7;
  int rl0  = (lane>>4)*4;
  unsigned pub_vo = (unsigned)(((kc_o*64 + (rl0|(hi<<4)))*8 + e_o)*4);
  int rbase = c*32 + mh*16 + rl0;
  float cst[4] = {0.f,0.f,0.f,0.f};

  unsigned* gbase = hx + (size_t)gid*16384;   // 2 parity buffers x 8192 dwords
  unsigned vo32 = (unsigned)lane*32u;
  // sentinel: producer js_s's (lane0,q0) tagged dword: (js_s>>1)*512 + (js_s&1)*256
  int js_s = lane&31;
  unsigned sent_vo = (unsigned)((((js_s>>1)*512) + (js_s&1)*256)*4);

  for(int s=0;s<TSEQ;s++){
    const unsigned* hin = gbase + (size_t)(s&1)*8192;
    unsigned* hout      = gbase + (size_t)((s+1)&1)*8192;
    unsigned tagexp = (unsigned)s;

    // prefetch token/table values for THIS step (independent of h)
    float tb[4][4];
    {
      int toks[4];
      #pragma unroll
      for(int q=0;q<4;q++) toks[q] = tokbase[(mh*16 + rl0 + q)*TSEQ + s];
      #pragma unroll
      for(int q=0;q<4;q++){
        const float* tbl = table + (size_t)toks[q]*GATES;
        tb[0][q]=tbl[j]; tb[1][q]=tbl[512+j]; tb[2][q]=tbl[1024+j]; tb[3][q]=tbl[1536+j];
      }
    }

    // ---- phase 1: cheap sentinel spin (4B/lane/attempt) ----
    while(true){
      unsigned sd;
      asm volatile(
        "global_load_dword %0, %1, %2 sc0 sc1\n\t"
        "s_waitcnt vmcnt(0)"
        : "=&v"(sd)
        : "v"(sent_vo), "s"((const void*)hin)
        : "memory");
      __builtin_amdgcn_sched_barrier(0);
      if(__all((int)((sd & 0xFFFFu) == tagexp))) break;
      __builtin_amdgcn_s_sleep(1);
    }

    // ---- phase 2: full pass with tag validation (rarely retries) ----
    uint4 ra[32];
    while(true){
      #pragma unroll
      for(int kc=0;kc<16;kc++){
        asm volatile(
          "global_load_dwordx4 %0, %2, %3 sc0 sc1\n\t"
          "global_load_dwordx4 %1, %2, %3 offset:16 sc0 sc1"
          : "=&v"(ra[2*kc]), "=&v"(ra[2*kc+1])
          : "v"(vo32), "s"((const void*)(hin + (size_t)kc*512))
          : "memory");
      }
      asm volatile("s_waitcnt vmcnt(0)" ::: "memory");
      __builtin_amdgcn_sched_barrier(0);     // rule-18 fence
      unsigned acc = 0u;
      #pragma unroll
      for(int i=0;i<32;i++)
        acc |= (ra[i].x ^ tagexp) | (ra[i].y ^ tagexp) | (ra[i].z ^ tagexp) | (ra[i].w ^ tagexp);
      if(__all((int)((acc & 0xFFFFu) == 0u))) break;
      __builtin_amdgcn_s_sleep(1);
    }

    // fused unpack + MFMA (one A-frag live at a time -> low VGPR pressure)
    f32x4 acc0={0,0,0,0}, acc1={0,0,0,0}, acc2={0,0,0,0}, acc3={0,0,0,0};
    #pragma unroll
    for(int kc=0;kc<16;kc++){
      uint4 pk_;
      pk_.x = (ra[2*kc].x  >>16) | (ra[2*kc].y  & 0xFFFF0000u);
      pk_.y = (ra[2*kc].z  >>16) | (ra[2*kc].w  & 0xFFFF0000u);
      pk_.z = (ra[2*kc+1].x>>16) | (ra[2*kc+1].y& 0xFFFF0000u);
      pk_.w = (ra[2*kc+1].z>>16) | (ra[2*kc+1].w& 0xFFFF0000u);
      bf16x8 afk = __builtin_bit_cast(bf16x8, pk_);
      acc0 = __builtin_amdgcn_mfma_f32_16x16x32_bf16(afk, wf[kc],    acc0, 0,0,0);
      acc1 = __builtin_amdgcn_mfma_f32_16x16x32_bf16(afk, wf[16+kc], acc1, 0,0,0);
      acc2 = __builtin_amdgcn_mfma_f32_16x16x32_bf16(afk, wf[32+kc], acc2, 0,0,0);
      bf16x8 b3 = *(const bf16x8*)(const void*)&wlds[((size_t)kc*64 + lane)*8];
      acc3 = __builtin_amdgcn_mfma_f32_16x16x32_bf16(afk, b3,        acc3, 0,0,0);
    }

    unsigned hv[4]; unsigned short hb16[4];
    int sc = s>>4, sl = s&15;
    unsigned tagw = (unsigned)(s+1);
    #pragma unroll
    for(int q=0;q<4;q++){
      float zi = acc0[q] + tb[0][q];
      float zf = acc1[q] + tb[1][q];
      float zg = acc2[q] + tb[2][q];
      float zo = acc3[q] + tb[3][q];
      float cn = sigf(zf)*cst[q] + sigf(zi)*tanhfast(zg);
      float h  = sigf(zo)*tanhfast(cn);
      cst[q] = cn;
      unsigned short hbv = f2bf(h);
      hb16[q] = hbv;
      hv[q] = ((unsigned)hbv<<16) | tagw;
    }
    // publish tagged dwords; tags self-validate at consumers
    asm volatile(
      "global_store_dword %[a], %[d0], %[sb] sc0 sc1\n\t"
      "global_store_dword %[a], %[d1], %[sb] offset:32 sc0 sc1\n\t"
      "global_store_dword %[a], %[d2], %[sb] offset:64 sc0 sc1\n\t"
      "global_store_dword %[a], %[d3], %[sb] offset:96 sc0 sc1"
      :: [a]"v"(pub_vo), [d0]"v"(hv[0]),[d1]"v"(hv[1]),[d2]"v"(hv[2]),[d3]"v"(hv[3]),
         [sb]"s"((void*)hout)
      : "memory");
    // archive (cached, off critical path)
    #pragma unroll
    for(int q=0;q<4;q++){
      int r = rbase + q;
      int mc = r*32 + sc;
      hsb[((size_t)(mc*16 + kc_o)*64 + (sl|(hi<<4)))*8 + e_o] = hb16[q];
    }
  }
}

// z = hsb @ W_out + b_out (bf16 MFMA) -> zb frags (16B stores via LDS
// transpose) + fused column-sum for mean.
__global__ __launch_bounds__(256) void zproj_mfma(const unsigned short* __restrict__ hsb,
        const unsigned short* __restrict__ woutswz, const float* __restrict__ b_out,
        unsigned short* __restrict__ zxA, unsigned short* __restrict__ zyB,
        float* __restrict__ zmean){
  __shared__ unsigned short zt[4][64*72];   // per-wave 64x64 bf16 tile, pad 72
  int tid = threadIdx.x, wv = tid>>6, lane = tid&63;
  int m0 = blockIdx.x*128 + (wv>>1)*64;
  int n0 = blockIdx.y*128 + (wv&1)*64;
  int mc0 = m0>>4, nc0 = n0>>4;
  const uint4* ha = (const uint4*)hsb;
  const uint4* wb = (const uint4*)woutswz;
  f32x4 acc[4][4];
  #pragma unroll
  for(int i=0;i<4;i++)
    #pragma unroll
    for(int k2=0;k2<4;k2++) acc[i][k2] = (f32x4){0,0,0,0};
  for(int kc=0;kc<16;kc++){
    bf16x8 a[4], b[4];
    #pragma unroll
    for(int i=0;i<4;i++){
      a[i] = __builtin_bit_cast(bf16x8, ha[((size_t)((mc0+i)*16 + kc))*64 + lane]);
      b[i] = __builtin_bit_cast(bf16x8, wb[((size_t)((nc0+i)*16 + kc))*64 + lane]);
    }
    #pragma unroll
    for(int mi=0;mi<4;mi++)
      #pragma unroll
      for(int ci=0;ci<4;ci++)
        acc[mi][ci] = __builtin_amdgcn_mfma_f32_16x16x32_bf16(a[mi], b[ci], acc[mi][ci], 0,0,0);
  }
  int r = m0>>9;
  bool isx = (r < NB);
  unsigned short* zb = isx ? zxA : zyB;
  int bb = isx ? r : r-NB;
  // stage bf16 tile to LDS + colsum
  #pragma unroll
  for(int ci=0;ci<4;ci++){
    int col = ci*16 + (lane&15);
    int n = n0 + col;
    float bo = b_out[n];
    float colsum = 0.f;
    #pragma unroll
    for(int mi=0;mi<4;mi++){
      #pragma unroll
      for(int q=0;q<4;q++){
        int row = mi*16 + (lane>>4)*4 + q;
        float zv = acc[mi][ci][q] + bo;
        colsum += acc[mi][ci][q];
        zt[wv][row*72 + col] = f2bf(zv);
      }
    }
    colsum += __shfl_xor(colsum, 16);
    colsum += __shfl_xor(colsum, 32);
    if((lane>>4)==0) atomicAdd(&zmean[(size_t)r*EDIM + n], colsum);
  }
  __syncthreads();
  // write out: 8 x 16B per thread (row = lane, 8 col-groups)
  int i = (m0 + lane)&511;
  size_t rowbase = ((size_t)(bb*32 + (i>>4))*16)*64*8;
  unsigned roff = (unsigned)(((i&15))*8);
  #pragma unroll
  for(int g=0;g<8;g++){
    int n = n0 + g*8;
    int kcz = n>>5, hi = (n>>3)&3;
    uint4 v = *(const uint4*)&zt[wv][lane*72 + g*8];
    *(uint4*)&zb[rowbase + (size_t)kcz*64*8 + (roff | ((unsigned)hi<<7))] = v;
  }
}

// theta (bf16 MFMA) fused with anti-diagonal transpose via LDS tile.
// thD[b][i+j][i] = zx[b][i,:] . zy[b][j,:]
#define DP 136
__global__ __launch_bounds__(256) void theta_diag_k(const unsigned short* __restrict__ zxA,
        const unsigned short* __restrict__ zyB, unsigned short* __restrict__ thD){
  __shared__ unsigned short t[128*DP];
  int tid = threadIdx.x, wv = tid>>6, lane = tid&63;
  int b = blockIdx.z;
  int i0 = blockIdx.x*128;
  int j0 = blockIdx.y*128;
  int iw = (wv>>1)*64;   // wave row offset in tile
  int jw = (wv&1)*64;    // wave col offset in tile
  int ic0 = (i0+iw)>>4, jc0 = (j0+jw)>>4;
  const uint4* pa = (const uint4*)zxA;
  const uint4* pb = (const uint4*)zyB;
  f32x4 acc[4][4];
  #pragma unroll
  for(int i=0;i<4;i++)
    #pragma unroll
    for(int k2=0;k2<4;k2++) acc[i][k2] = (f32x4){0,0,0,0};
  for(int kc=0;kc<16;kc++){
    bf16x8 a[4], bfr[4];
    #pragma unroll
    for(int i=0;i<4;i++){
      a[i]   = __builtin_bit_cast(bf16x8, pa[((size_t)(b*32 + ic0+i)*16 + kc)*64 + lane]);
      bfr[i] = __builtin_bit_cast(bf16x8, pb[((size_t)(b*32 + jc0+i)*16 + kc)*64 + lane]);
    }
    #pragma unroll
    for(int mi=0;mi<4;mi++)
      #pragma unroll
      for(int ci=0;ci<4;ci++)
        acc[mi][ci] = __builtin_amdgcn_mfma_f32_16x16x32_bf16(a[mi], bfr[ci], acc[mi][ci], 0,0,0);
  }
  // stage tile to LDS (bf16)
  #pragma unroll
  for(int mi=0;mi<4;mi++){
    #pragma unroll
    for(int ci=0;ci<4;ci++){
      #pragma unroll
      for(int q=0;q<4;q++){
        int row = iw + mi*16 + (lane>>4)*4 + q;
        int col = jw + ci*16 + (lane&15);
        t[row*DP + col] = f2bf(acc[mi][ci][q]);
      }
    }
  }
  __syncthreads();
  // write anti-diagonals: 256 threads = 2 u's per iteration
  int t2 = tid&127;
  for(int u2=0;u2<256;u2+=2){
    int u = u2 + (tid>>7);
    if(u<255){
      int d = i0 + j0 + u;
      int ibeg = (u>127) ? (d - j0 - 127) : i0;
      int iend = (u<128) ? (d - j0)       : (i0+127);
      int len = iend - ibeg + 1;
      if(t2 < len){
        int i = ibeg + t2;
        thD[((size_t)b*1023 + d)*TSEQ + i] = t[(i-i0)*DP + (d-i-j0)];
      }
    }
  }
}

__global__ __launch_bounds__(256) void gap_k(const float* __restrict__ zmean,
        const float* __restrict__ b_out, const float* __restrict__ W_gap,
        const float* __restrict__ b_gap, float* __restrict__ Aout){
  __shared__ float red[256];
  int b = blockIdx.x;
  int tid = threadIdx.x;
  float acc=0.f;
  for(int i=tid;i<2*EDIM;i+=256){
    int e = (i<EDIM)? i : i-EDIM;
    float msum = (i<EDIM)? zmean[(size_t)b*EDIM+e] : zmean[(size_t)(b+NB)*EDIM+e];
    float m = msum*(1.0f/TSEQ) + b_out[e];
    acc = fmaf(m, W_gap[i], acc);
  }
  red[tid]=acc; __syncthreads();
  for(int s=128;s>0;s>>=1){ if(tid<s) red[tid]+=red[tid+s]; __syncthreads(); }
  if(tid==0) Aout[b] = red[0] + b_gap[0];
}

// NW: one wave per batch; bf16 diagonal theta; 16-deep register prefetch
// pipeline (named bufs, static indexing) -> 2x bytes in flight vs 8-deep.
__global__ __launch_bounds__(64) void nw_k(const unsigned short* __restrict__ thD,
        const float* __restrict__ Aout, float* __restrict__ out){
  const float L2E = 1.4426950408889634f, LN2 = 0.6931471805599453f;
  int b = blockIdx.x;
  int lane = threadIdx.x;
  float A = Aout[b];
  const unsigned short* thb = thD + (size_t)b*1023*TSEQ;
  float p1[8], p2[8];
  #pragma unroll
  for(int i=0;i<8;i++){ p1[i]=NEGV; p2[i]=NEGV; }
  float p1_0 = NEGV, p2_0 = 0.0f;
  uint4 t0  = *(const uint4*)&thb[(size_t) 0*TSEQ + lane*8];
  uint4 t1  = *(const uint4*)&thb[(size_t) 1*TSEQ + lane*8];
  uint4 t2  = *(const uint4*)&thb[(size_t) 2*TSEQ + lane*8];
  uint4 t3  = *(const uint4*)&thb[(size_t) 3*TSEQ + lane*8];
  uint4 t4  = *(const uint4*)&thb[(size_t) 4*TSEQ + lane*8];
  uint4 t5  = *(const uint4*)&thb[(size_t) 5*TSEQ + lane*8];
  uint4 t6  = *(const uint4*)&thb[(size_t) 6*TSEQ + lane*8];
  uint4 t7  = *(const uint4*)&thb[(size_t) 7*TSEQ + lane*8];
  uint4 t8  = *(const uint4*)&thb[(size_t) 8*TSEQ + lane*8];
  uint4 t9  = *(const uint4*)&thb[(size_t) 9*TSEQ + lane*8];
  uint4 t10 = *(const uint4*)&thb[(size_t)10*TSEQ + lane*8];
  uint4 t11 = *(const uint4*)&thb[(size_t)11*TSEQ + lane*8];
  uint4 t12 = *(const uint4*)&thb[(size_t)12*TSEQ + lane*8];
  uint4 t13 = *(const uint4*)&thb[(size_t)13*TSEQ + lane*8];
  uint4 t14 = *(const uint4*)&thb[(size_t)14*TSEQ + lane*8];
  uint4 t15 = *(const uint4*)&thb[(size_t)15*TSEQ + lane*8];
  int k = 2;

#define PF(row) ((size_t)((row)>1022?1022:(row))*TSEQ + lane*8)
#define NWCORE(TB) { \
    float td[8]; \
    td[0]=bf2f((unsigned short)(TB.x&0xFFFF)); td[1]=bf2f((unsigned short)(TB.x>>16)); \
    td[2]=bf2f((unsigned short)(TB.y&0xFFFF)); td[3]=bf2f((unsigned short)(TB.y>>16)); \
    td[4]=bf2f((unsigned short)(TB.z&0xFFFF)); td[5]=bf2f((unsigned short)(TB.z>>16)); \
    td[6]=bf2f((unsigned short)(TB.w&0xFFFF)); td[7]=bf2f((unsigned short)(TB.w>>16)); \
    float pm1 = __shfl_up(p1[7],1); \
    float pm2 = __shfl_up(p2[7],1); \
    if(lane==0){ pm1 = p1_0; pm2 = p2_0; } \
    float cur[8]; \
    _Pragma("unroll") \
    for(int cx=0;cx<8;cx++){ \
      int ii = lane*8+1+cx; \
      int jq = k-ii; \
      bool valid = (jq>=1)&&(jq<=512); \
      float a_ = (cx==0? pm1 : p1[cx-1]) + A; \
      float bb = (cx==0? pm2 : p2[cx-1]); \
      float cc = p1[cx] + A; \
      float mm = fmaxf(fmaxf(a_,bb),cc); \
      float sum = exp2f((a_-mm)*L2E) + exp2f((bb-mm)*L2E) + exp2f((cc-mm)*L2E); \
      float v = mm + log2f(sum)*LN2; \
      cur[cx] = valid ? td[cx] + v : NEGV; \
    } \
    _Pragma("unroll") \
    for(int cx=0;cx<8;cx++){ p2[cx]=p1[cx]; p1[cx]=cur[cx]; } \
    p2_0 = p1_0; p1_0 = NEGV; \
    k++; }

  for(int d0=0; d0<1008; d0+=16){
    NWCORE(t0);  t0  = *(const uint4*)&thb[PF(d0+16)];
    NWCORE(t1);  t1  = *(const uint4*)&thb[PF(d0+17)];
    NWCORE(t2);  t2  = *(const uint4*)&thb[PF(d0+18)];
    NWCORE(t3);  t3  = *(const uint4*)&thb[PF(d0+19)];
    NWCORE(t4);  t4  = *(const uint4*)&thb[PF(d0+20)];
    NWCORE(t5);  t5  = *(const uint4*)&thb[PF(d0+21)];
    NWCORE(t6);  t6  = *(const uint4*)&thb[PF(d0+22)];
    NWCORE(t7);  t7  = *(const uint4*)&thb[PF(d0+23)];
    NWCORE(t8);  t8  = *(const uint4*)&thb[PF(d0+24)];
    NWCORE(t9);  t9  = *(const uint4*)&thb[PF(d0+25)];
    NWCORE(t10); t10 = *(const uint4*)&thb[PF(d0+26)];
    NWCORE(t11); t11 = *(const uint4*)&thb[PF(d0+27)];
    NWCORE(t12); t12 = *(const uint4*)&thb[PF(d0+28)];
    NWCORE(t13); t13 = *(const uint4*)&thb[PF(d0+29)];
    NWCORE(t14); t14 = *(const uint4*)&thb[PF(d0+30)];
    NWCORE(t15); t15 = *(const uint4*)&thb[PF(d0+31)];
  }
  // tail: diagonals 1008..1022 (k = 1010..1024)
  NWCORE(t0);  NWCORE(t1);  NWCORE(t2);  NWCORE(t3);
  NWCORE(t4);  NWCORE(t5);  NWCORE(t6);  NWCORE(t7);
  NWCORE(t8);  NWCORE(t9);  NWCORE(t10); NWCORE(t11);
  NWCORE(t12); NWCORE(t13); NWCORE(t14);
  if(lane==63) out[b] = p1[7];
#undef NWCORE
#undef PF
}

extern "C" void kernel_launch(void* const* d_in, const int* in_sizes, int n_in,
                              void* d_out, int out_size, void* d_ws, size_t ws_size,
                              hipStream_t stream) {
  (void)in_sizes; (void)n_in; (void)out_size; (void)ws_size;
  const int*   x      = (const int*)d_in[0];
  const int*   y      = (const int*)d_in[1];
  const float* emb    = (const float*)d_in[2];
  const float* W_ih   = (const float*)d_in[3];
  const float* W_hh   = (const float*)d_in[4];
  const float* b_lstm = (const float*)d_in[5];
  const float* W_out  = (const float*)d_in[6];
  const float* b_out  = (const float*)d_in[7];
  const float* W_gap  = (const float*)d_in[8];
  const float* b_gap  = (const float*)d_in[9];
  float* out = (float*)d_out;

  char* ws = (char*)d_ws;
  const size_t OFF_TABLE = 0;                         // 180224 (pad 184320)
  const size_t OFF_WSWZ  = 184320;                    // 2MB
  const size_t OFF_WOUT  = OFF_WSWZ  + 2097152;       // 512KB
  const size_t OFF_HX    = OFF_WOUT  + 524288;        // 256KB tagged h exchange
  const size_t OFF_HSB   = OFF_HX    + 262144;        // 32MB
  const size_t OFF_ZXA   = OFF_HSB   + 33554432;      // 16MB
  const size_t OFF_ZYB   = OFF_ZXA   + 16777216;      // 16MB
  const size_t OFF_THD   = OFF_ZYB   + 16777216;      // 33.5MB bf16 theta diag
  const size_t OFF_ZMEAN = OFF_THD   + 33521664;      // 128KB f32 col-sums
  const size_t OFF_AOUT  = OFF_ZMEAN + 131072;        // 128B
  float* table = (float*)(ws + OFF_TABLE);
  unsigned short* Wswz    = (unsigned short*)(ws + OFF_WSWZ);
  unsigned short* woutswz = (unsigned short*)(ws + OFF_WOUT);
  unsigned* hx = (unsigned*)(ws + OFF_HX);
  unsigned short* hsb  = (unsigned short*)(ws + OFF_HSB);
  unsigned short* zxA  = (unsigned short*)(ws + OFF_ZXA);
  unsigned short* zyB  = (unsigned short*)(ws + OFF_ZYB);
  unsigned short* thD  = (unsigned short*)(ws + OFF_THD);
  float* zmean = (float*)(ws + OFF_ZMEAN);
  float* Aout  = (float*)(ws + OFF_AOUT);

  hipMemsetAsync(hx, 0, 262144, stream);     // tags/data = 0 each launch (graph replay)
  hipMemsetAsync(zmean, 0, 131072, stream);  // column-sum accumulators

  table_k<<<dim3(8,22), 256, 0, stream>>>(emb, W_ih, b_lstm, table);
  wprep_k<<<2048, 64, 0, stream>>>(W_hh, Wswz);
  wprep2_k<<<512, 64, 0, stream>>>(W_out, woutswz);
  lstm_wave<<<128, 64, 0, stream>>>(x, y, table, Wswz, hx, hsb);
  zproj_mfma<<<dim3(256,4), 256, 0, stream>>>(hsb, woutswz, b_out, zxA, zyB, zmean);
  theta_diag_k<<<dim3(4,4,32), 256, 0, stream>>>(zxA, zyB, thD);
  gap_k<<<32, 256, 0, stream>>>(zmean, b_out, W_gap, b_gap, Aout);
  nw_k<<<32, 64, 0, stream>>>(thD, Aout, out);
}

// Round 18
// 2474.441 us; speedup vs baseline: 1.0447x; 1.0447x over previous
//
#include <hip/hip_runtime.h>
#include <math.h>

#define TSEQ 512
#define HDIM 512
#define EDIM 512
#define NB   32
#define ROWS 64
#define GATES 2048
#define NEGV -1000000000.0f

typedef __attribute__((ext_vector_type(8))) short bf16x8;
typedef __attribute__((ext_vector_type(4))) float f32x4;

__device__ __forceinline__ float sigf(float x){ return __builtin_amdgcn_rcpf(1.0f + __expf(-x)); }

__device__ __forceinline__ float tanhfast(float x){
  float t = __expf(-2.0f*fabsf(x));
  float r = (1.0f - t)*__builtin_amdgcn_rcpf(1.0f + t);
  return copysignf(r, x);
}

__device__ __forceinline__ unsigned short f2bf(float f){
  unsigned int u = __builtin_bit_cast(unsigned int, f);
  unsigned int r = (u + 0x7fff + ((u>>16)&1)) >> 16;
  return (unsigned short)r;
}

__device__ __forceinline__ float bf2f(unsigned short v){
  unsigned int u = ((unsigned int)v)<<16;
  return __builtin_bit_cast(float, u);
}

// table[v][j] = sum_k emb[v][k] * W_ih[k][j] + b_lstm[j]   (fp32)
__global__ __launch_bounds__(256) void table_k(const float* __restrict__ emb,
        const float* __restrict__ W_ih, const float* __restrict__ b_lstm,
        float* __restrict__ table){
  int j = blockIdx.x*256 + threadIdx.x;
  int v = blockIdx.y;
  float acc = b_lstm[j];
  #pragma unroll 4
  for(int k=0;k<EDIM;k++) acc = fmaf(emb[v*EDIM+k], W_ih[(size_t)k*GATES+j], acc);
  table[(size_t)v*GATES+j] = acc;
}

// W_hh -> bf16 B-fragment order. cid = js*64 + g*16 + kc.
__global__ __launch_bounds__(64) void wprep_k(const float* __restrict__ W_hh,
        unsigned short* __restrict__ Wswz){
  int cid = blockIdx.x;           // 0..2047
  int lane = threadIdx.x;
  int js = cid>>6, g = (cid>>4)&3, kc = cid&15;
  int col = g*512 + js*16 + (lane&15);
  int kbase = kc*32 + (lane>>4)*8;
  unsigned short v[8];
  #pragma unroll
  for(int e=0;e<8;e++) v[e] = f2bf(W_hh[(size_t)(kbase+e)*GATES + col]);
  *(uint4*)&Wswz[((size_t)cid*64 + lane)*8] = *(const uint4*)v;
}

// W_out -> bf16 B-fragment order. cid = nc*16 + kc.
__global__ __launch_bounds__(64) void wprep2_k(const float* __restrict__ W_out,
        unsigned short* __restrict__ wsw){
  int cid = blockIdx.x;           // 0..511
  int lane = threadIdx.x;
  int nc = cid>>4, kc = cid&15;
  int col = nc*16 + (lane&15);
  int kb = kc*32 + (lane>>4)*8;
  unsigned short v[8];
  #pragma unroll
  for(int e=0;e<8;e++) v[e] = f2bf(W_out[(size_t)(kb+e)*EDIM + col]);
  *(uint4*)&wsw[((size_t)cid*64 + lane)*8] = *(const uint4*)v;
}

// Persistent LSTM (R14-proven): 128 single-wave WGs. W gates 0-2 in 192 VGPRs,
// gate 3 in 16KB LDS. Tagged-dword h exchange.
// Two-phase wait: 4B/lane sentinel spin, then ONE validated full pass.
__global__ __launch_bounds__(64,1) void lstm_wave(const int* __restrict__ x, const int* __restrict__ y,
        const float* __restrict__ table, const unsigned short* __restrict__ Wswz,
        unsigned* __restrict__ hx, unsigned short* __restrict__ hsb){
  __shared__ unsigned short wlds[8192];   // 16KB: gate 3 [kc][lane][8]
  int w = blockIdx.x;            // 0..127
  int c = w>>6, mh = (w>>5)&1, js = w&31;
  int gid = c*2 + mh;
  int lane = threadIdx.x;

  // gates 0..2 -> registers (48 x bf16x8 = 192 VGPRs)
  bf16x8 wf[48];
  {
    const unsigned short* wp = Wswz + (size_t)js*32768;
    #pragma unroll
    for(int g=0;g<3;g++)
      #pragma unroll
      for(int kc=0;kc<16;kc++)
        wf[g*16+kc] = *(const bf16x8*)(const void*)&wp[((size_t)(g*16+kc)*64 + lane)*8];
  }
  { // gate 3 -> LDS (contiguous 16KB)
    const uint4* src = (const uint4*)(Wswz + (size_t)js*32768 + 48*512);
    uint4* dst = (uint4*)wlds;
    #pragma unroll
    for(int i=0;i<16;i++) dst[lane + i*64] = src[lane + i*64];
  }
  __syncthreads();

  const int* tokbase = c ? y : x;
  int jloc = lane&15;
  int j    = js*16 + jloc;
  int hi   = (j>>3)&3;
  int kc_o = j>>5;
  int e_o  = j&7;
  int rl0  = (lane>>4)*4;
  unsigned pub_vo = (unsigned)(((kc_o*64 + (rl0|(hi<<4)))*8 + e_o)*4);
  int rbase = c*32 + mh*16 + rl0;
  float cst[4] = {0.f,0.f,0.f,0.f};

  unsigned* gbase = hx + (size_t)gid*16384;   // 2 parity buffers x 8192 dwords
  unsigned vo32 = (unsigned)lane*32u;
  // sentinel: producer js_s's (lane0,q0) tagged dword: (js_s>>1)*512 + (js_s&1)*256
  int js_s = lane&31;
  unsigned sent_vo = (unsigned)((((js_s>>1)*512) + (js_s&1)*256)*4);

  for(int s=0;s<TSEQ;s++){
    const unsigned* hin = gbase + (size_t)(s&1)*8192;
    unsigned* hout      = gbase + (size_t)((s+1)&1)*8192;
    unsigned tagexp = (unsigned)s;

    // prefetch token/table values for THIS step (independent of h)
    float tb[4][4];
    {
      int toks[4];
      #pragma unroll
      for(int q=0;q<4;q++) toks[q] = tokbase[(mh*16 + rl0 + q)*TSEQ + s];
      #pragma unroll
      for(int q=0;q<4;q++){
        const float* tbl = table + (size_t)toks[q]*GATES;
        tb[0][q]=tbl[j]; tb[1][q]=tbl[512+j]; tb[2][q]=tbl[1024+j]; tb[3][q]=tbl[1536+j];
      }
    }

    // ---- phase 1: cheap sentinel spin (4B/lane/attempt) ----
    while(true){
      unsigned sd;
      asm volatile(
        "global_load_dword %0, %1, %2 sc0 sc1\n\t"
        "s_waitcnt vmcnt(0)"
        : "=&v"(sd)
        : "v"(sent_vo), "s"((const void*)hin)
        : "memory");
      __builtin_amdgcn_sched_barrier(0);
      if(__all((int)((sd & 0xFFFFu) == tagexp))) break;
      __builtin_amdgcn_s_sleep(1);
    }

    // ---- phase 2: full pass with tag validation (rarely retries) ----
    uint4 ra[32];
    while(true){
      #pragma unroll
      for(int kc=0;kc<16;kc++){
        asm volatile(
          "global_load_dwordx4 %0, %2, %3 sc0 sc1\n\t"
          "global_load_dwordx4 %1, %2, %3 offset:16 sc0 sc1"
          : "=&v"(ra[2*kc]), "=&v"(ra[2*kc+1])
          : "v"(vo32), "s"((const void*)(hin + (size_t)kc*512))
          : "memory");
      }
      asm volatile("s_waitcnt vmcnt(0)" ::: "memory");
      __builtin_amdgcn_sched_barrier(0);     // rule-18 fence
      unsigned acc = 0u;
      #pragma unroll
      for(int i=0;i<32;i++)
        acc |= (ra[i].x ^ tagexp) | (ra[i].y ^ tagexp) | (ra[i].z ^ tagexp) | (ra[i].w ^ tagexp);
      if(__all((int)((acc & 0xFFFFu) == 0u))) break;
      __builtin_amdgcn_s_sleep(1);
    }

    // fused unpack + MFMA (one A-frag live at a time -> low VGPR pressure)
    f32x4 acc0={0,0,0,0}, acc1={0,0,0,0}, acc2={0,0,0,0}, acc3={0,0,0,0};
    #pragma unroll
    for(int kc=0;kc<16;kc++){
      uint4 pk_;
      pk_.x = (ra[2*kc].x  >>16) | (ra[2*kc].y  & 0xFFFF0000u);
      pk_.y = (ra[2*kc].z  >>16) | (ra[2*kc].w  & 0xFFFF0000u);
      pk_.z = (ra[2*kc+1].x>>16) | (ra[2*kc+1].y& 0xFFFF0000u);
      pk_.w = (ra[2*kc+1].z>>16) | (ra[2*kc+1].w& 0xFFFF0000u);
      bf16x8 afk = __builtin_bit_cast(bf16x8, pk_);
      acc0 = __builtin_amdgcn_mfma_f32_16x16x32_bf16(afk, wf[kc],    acc0, 0,0,0);
      acc1 = __builtin_amdgcn_mfma_f32_16x16x32_bf16(afk, wf[16+kc], acc1, 0,0,0);
      acc2 = __builtin_amdgcn_mfma_f32_16x16x32_bf16(afk, wf[32+kc], acc2, 0,0,0);
      bf16x8 b3 = *(const bf16x8*)(const void*)&wlds[((size_t)kc*64 + lane)*8];
      acc3 = __builtin_amdgcn_mfma_f32_16x16x32_bf16(afk, b3,        acc3, 0,0,0);
    }

    unsigned hv[4]; unsigned short hb16[4];
    int sc = s>>4, sl = s&15;
    unsigned tagw = (unsigned)(s+1);
    #pragma unroll
    for(int q=0;q<4;q++){
      float zi = acc0[q] + tb[0][q];
      float zf = acc1[q] + tb[1][q];
      float zg = acc2[q] + tb[2][q];
      float zo = acc3[q] + tb[3][q];
      float cn = sigf(zf)*cst[q] + sigf(zi)*tanhfast(zg);
      float h  = sigf(zo)*tanhfast(cn);
      cst[q] = cn;
      unsigned short hbv = f2bf(h);
      hb16[q] = hbv;
      hv[q] = ((unsigned)hbv<<16) | tagw;
    }
    // publish tagged dwords; tags self-validate at consumers
    asm volatile(
      "global_store_dword %[a], %[d0], %[sb] sc0 sc1\n\t"
      "global_store_dword %[a], %[d1], %[sb] offset:32 sc0 sc1\n\t"
      "global_store_dword %[a], %[d2], %[sb] offset:64 sc0 sc1\n\t"
      "global_store_dword %[a], %[d3], %[sb] offset:96 sc0 sc1"
      :: [a]"v"(pub_vo), [d0]"v"(hv[0]),[d1]"v"(hv[1]),[d2]"v"(hv[2]),[d3]"v"(hv[3]),
         [sb]"s"((void*)hout)
      : "memory");
    // archive (cached, off critical path)
    #pragma unroll
    for(int q=0;q<4;q++){
      int r = rbase + q;
      int mc = r*32 + sc;
      hsb[((size_t)(mc*16 + kc_o)*64 + (sl|(hi<<4)))*8 + e_o] = hb16[q];
    }
  }
}

// z = hsb @ W_out + b_out (bf16 MFMA) -> zb frags (16B stores via LDS
// transpose) + fused column-sum for mean.
__global__ __launch_bounds__(256) void zproj_mfma(const unsigned short* __restrict__ hsb,
        const unsigned short* __restrict__ woutswz, const float* __restrict__ b_out,
        unsigned short* __restrict__ zxA, unsigned short* __restrict__ zyB,
        float* __restrict__ zmean){
  __shared__ unsigned short zt[4][64*72];   // per-wave 64x64 bf16 tile, pad 72
  int tid = threadIdx.x, wv = tid>>6, lane = tid&63;
  int m0 = blockIdx.x*128 + (wv>>1)*64;
  int n0 = blockIdx.y*128 + (wv&1)*64;
  int mc0 = m0>>4, nc0 = n0>>4;
  const uint4* ha = (const uint4*)hsb;
  const uint4* wb = (const uint4*)woutswz;
  f32x4 acc[4][4];
  #pragma unroll
  for(int i=0;i<4;i++)
    #pragma unroll
    for(int k2=0;k2<4;k2++) acc[i][k2] = (f32x4){0,0,0,0};
  for(int kc=0;kc<16;kc++){
    bf16x8 a[4], b[4];
    #pragma unroll
    for(int i=0;i<4;i++){
      a[i] = __builtin_bit_cast(bf16x8, ha[((size_t)((mc0+i)*16 + kc))*64 + lane]);
      b[i] = __builtin_bit_cast(bf16x8, wb[((size_t)((nc0+i)*16 + kc))*64 + lane]);
    }
    #pragma unroll
    for(int mi=0;mi<4;mi++)
      #pragma unroll
      for(int ci=0;ci<4;ci++)
        acc[mi][ci] = __builtin_amdgcn_mfma_f32_16x16x32_bf16(a[mi], b[ci], acc[mi][ci], 0,0,0);
  }
  int r = m0>>9;
  bool isx = (r < NB);
  unsigned short* zb = isx ? zxA : zyB;
  int bb = isx ? r : r-NB;
  // stage bf16 tile to LDS + colsum
  #pragma unroll
  for(int ci=0;ci<4;ci++){
    int col = ci*16 + (lane&15);
    int n = n0 + col;
    float bo = b_out[n];
    float colsum = 0.f;
    #pragma unroll
    for(int mi=0;mi<4;mi++){
      #pragma unroll
      for(int q=0;q<4;q++){
        int row = mi*16 + (lane>>4)*4 + q;
        float zv = acc[mi][ci][q] + bo;
        colsum += acc[mi][ci][q];
        zt[wv][row*72 + col] = f2bf(zv);
      }
    }
    colsum += __shfl_xor(colsum, 16);
    colsum += __shfl_xor(colsum, 32);
    if((lane>>4)==0) atomicAdd(&zmean[(size_t)r*EDIM + n], colsum);
  }
  __syncthreads();
  // write out: 8 x 16B per thread (row = lane, 8 col-groups)
  int i = (m0 + lane)&511;
  size_t rowbase = ((size_t)(bb*32 + (i>>4))*16)*64*8;
  unsigned roff = (unsigned)(((i&15))*8);
  #pragma unroll
  for(int g=0;g<8;g++){
    int n = n0 + g*8;
    int kcz = n>>5, hi = (n>>3)&3;
    uint4 v = *(const uint4*)&zt[wv][lane*72 + g*8];
    *(uint4*)&zb[rowbase + (size_t)kcz*64*8 + (roff | ((unsigned)hi<<7))] = v;
  }
}

// theta (bf16 MFMA) fused with anti-diagonal transpose via LDS tile.
// thD[b][i+j][i] = zx[b][i,:] . zy[b][j,:]
#define DP 136
__global__ __launch_bounds__(256) void theta_diag_k(const unsigned short* __restrict__ zxA,
        const unsigned short* __restrict__ zyB, unsigned short* __restrict__ thD){
  __shared__ unsigned short t[128*DP];
  int tid = threadIdx.x, wv = tid>>6, lane = tid&63;
  int b = blockIdx.z;
  int i0 = blockIdx.x*128;
  int j0 = blockIdx.y*128;
  int iw = (wv>>1)*64;   // wave row offset in tile
  int jw = (wv&1)*64;    // wave col offset in tile
  int ic0 = (i0+iw)>>4, jc0 = (j0+jw)>>4;
  const uint4* pa = (const uint4*)zxA;
  const uint4* pb = (const uint4*)zyB;
  f32x4 acc[4][4];
  #pragma unroll
  for(int i=0;i<4;i++)
    #pragma unroll
    for(int k2=0;k2<4;k2++) acc[i][k2] = (f32x4){0,0,0,0};
  for(int kc=0;kc<16;kc++){
    bf16x8 a[4], bfr[4];
    #pragma unroll
    for(int i=0;i<4;i++){
      a[i]   = __builtin_bit_cast(bf16x8, pa[((size_t)(b*32 + ic0+i)*16 + kc)*64 + lane]);
      bfr[i] = __builtin_bit_cast(bf16x8, pb[((size_t)(b*32 + jc0+i)*16 + kc)*64 + lane]);
    }
    #pragma unroll
    for(int mi=0;mi<4;mi++)
      #pragma unroll
      for(int ci=0;ci<4;ci++)
        acc[mi][ci] = __builtin_amdgcn_mfma_f32_16x16x32_bf16(a[mi], bfr[ci], acc[mi][ci], 0,0,0);
  }
  // stage tile to LDS (bf16)
  #pragma unroll
  for(int mi=0;mi<4;mi++){
    #pragma unroll
    for(int ci=0;ci<4;ci++){
      #pragma unroll
      for(int q=0;q<4;q++){
        int row = iw + mi*16 + (lane>>4)*4 + q;
        int col = jw + ci*16 + (lane&15);
        t[row*DP + col] = f2bf(acc[mi][ci][q]);
      }
    }
  }
  __syncthreads();
  // write anti-diagonals: 256 threads = 2 u's per iteration
  int t2 = tid&127;
  for(int u2=0;u2<256;u2+=2){
    int u = u2 + (tid>>7);
    if(u<255){
      int d = i0 + j0 + u;
      int ibeg = (u>127) ? (d - j0 - 127) : i0;
      int iend = (u<128) ? (d - j0)       : (i0+127);
      int len = iend - ibeg + 1;
      if(t2 < len){
        int i = ibeg + t2;
        thD[((size_t)b*1023 + d)*TSEQ + i] = t[(i-i0)*DP + (d-i-j0)];
      }
    }
  }
}

__global__ __launch_bounds__(256) void gap_k(const float* __restrict__ zmean,
        const float* __restrict__ b_out, const float* __restrict__ W_gap,
        const float* __restrict__ b_gap, float* __restrict__ Aout){
  __shared__ float red[256];
  int b = blockIdx.x;
  int tid = threadIdx.x;
  float acc=0.f;
  for(int i=tid;i<2*EDIM;i+=256){
    int e = (i<EDIM)? i : i-EDIM;
    float msum = (i<EDIM)? zmean[(size_t)b*EDIM+e] : zmean[(size_t)(b+NB)*EDIM+e];
    float m = msum*(1.0f/TSEQ) + b_out[e];
    acc = fmaf(m, W_gap[i], acc);
  }
  red[tid]=acc; __syncthreads();
  for(int s=128;s>0;s>>=1){ if(tid<s) red[tid]+=red[tid+s]; __syncthreads(); }
  if(tid==0) Aout[b] = red[0] + b_gap[0];
}

// NW: one wave per batch; bf16 diagonal theta; 8-deep register prefetch
// pipeline (named bufs, static indexing) to hide HBM latency.
__global__ __launch_bounds__(64) void nw_k(const unsigned short* __restrict__ thD,
        const float* __restrict__ Aout, float* __restrict__ out){
  const float L2E = 1.4426950408889634f, LN2 = 0.6931471805599453f;
  int b = blockIdx.x;
  int lane = threadIdx.x;
  float A = Aout[b];
  const unsigned short* thb = thD + (size_t)b*1023*TSEQ;
  float p1[8], p2[8];
  #pragma unroll
  for(int i=0;i<8;i++){ p1[i]=NEGV; p2[i]=NEGV; }
  float p1_0 = NEGV, p2_0 = 0.0f;
  uint4 t0 = *(const uint4*)&thb[(size_t)0*TSEQ + lane*8];
  uint4 t1 = *(const uint4*)&thb[(size_t)1*TSEQ + lane*8];
  uint4 t2 = *(const uint4*)&thb[(size_t)2*TSEQ + lane*8];
  uint4 t3 = *(const uint4*)&thb[(size_t)3*TSEQ + lane*8];
  uint4 t4 = *(const uint4*)&thb[(size_t)4*TSEQ + lane*8];
  uint4 t5 = *(const uint4*)&thb[(size_t)5*TSEQ + lane*8];
  uint4 t6 = *(const uint4*)&thb[(size_t)6*TSEQ + lane*8];
  uint4 t7 = *(const uint4*)&thb[(size_t)7*TSEQ + lane*8];
  int k = 2;

#define PF(row) ((size_t)((row)>1022?1022:(row))*TSEQ + lane*8)
#define NWCORE(TB) { \
    float td[8]; \
    td[0]=bf2f((unsigned short)(TB.x&0xFFFF)); td[1]=bf2f((unsigned short)(TB.x>>16)); \
    td[2]=bf2f((unsigned short)(TB.y&0xFFFF)); td[3]=bf2f((unsigned short)(TB.y>>16)); \
    td[4]=bf2f((unsigned short)(TB.z&0xFFFF)); td[5]=bf2f((unsigned short)(TB.z>>16)); \
    td[6]=bf2f((unsigned short)(TB.w&0xFFFF)); td[7]=bf2f((unsigned short)(TB.w>>16)); \
    float pm1 = __shfl_up(p1[7],1); \
    float pm2 = __shfl_up(p2[7],1); \
    if(lane==0){ pm1 = p1_0; pm2 = p2_0; } \
    float cur[8]; \
    _Pragma("unroll") \
    for(int cx=0;cx<8;cx++){ \
      int ii = lane*8+1+cx; \
      int jq = k-ii; \
      bool valid = (jq>=1)&&(jq<=512); \
      float a_ = (cx==0? pm1 : p1[cx-1]) + A; \
      float bb = (cx==0? pm2 : p2[cx-1]); \
      float cc = p1[cx] + A; \
      float mm = fmaxf(fmaxf(a_,bb),cc); \
      float sum = exp2f((a_-mm)*L2E) + exp2f((bb-mm)*L2E) + exp2f((cc-mm)*L2E); \
      float v = mm + log2f(sum)*LN2; \
      cur[cx] = valid ? td[cx] + v : NEGV; \
    } \
    _Pragma("unroll") \
    for(int cx=0;cx<8;cx++){ p2[cx]=p1[cx]; p1[cx]=cur[cx]; } \
    p2_0 = p1_0; p1_0 = NEGV; \
    k++; }

  for(int d0=0; d0<1016; d0+=8){
    NWCORE(t0); t0 = *(const uint4*)&thb[PF(d0+ 8)];
    NWCORE(t1); t1 = *(const uint4*)&thb[PF(d0+ 9)];
    NWCORE(t2); t2 = *(const uint4*)&thb[PF(d0+10)];
    NWCORE(t3); t3 = *(const uint4*)&thb[PF(d0+11)];
    NWCORE(t4); t4 = *(const uint4*)&thb[PF(d0+12)];
    NWCORE(t5); t5 = *(const uint4*)&thb[PF(d0+13)];
    NWCORE(t6); t6 = *(const uint4*)&thb[PF(d0+14)];
    NWCORE(t7); t7 = *(const uint4*)&thb[PF(d0+15)];
  }
  // tail: diagonals 1016..1022 (k = 1018..1024)
  NWCORE(t0); NWCORE(t1); NWCORE(t2); NWCORE(t3);
  NWCORE(t4); NWCORE(t5); NWCORE(t6);
  if(lane==63) out[b] = p1[7];
#undef NWCORE
#undef PF
}

extern "C" void kernel_launch(void* const* d_in, const int* in_sizes, int n_in,
                              void* d_out, int out_size, void* d_ws, size_t ws_size,
                              hipStream_t stream) {
  (void)in_sizes; (void)n_in; (void)out_size; (void)ws_size;
  const int*   x      = (const int*)d_in[0];
  const int*   y      = (const int*)d_in[1];
  const float* emb    = (const float*)d_in[2];
  const float* W_ih   = (const float*)d_in[3];
  const float* W_hh   = (const float*)d_in[4];
  const float* b_lstm = (const float*)d_in[5];
  const float* W_out  = (const float*)d_in[6];
  const float* b_out  = (const float*)d_in[7];
  const float* W_gap  = (const float*)d_in[8];
  const float* b_gap  = (const float*)d_in[9];
  float* out = (float*)d_out;

  char* ws = (char*)d_ws;
  const size_t OFF_TABLE = 0;                         // 180224 (pad 184320)
  const size_t OFF_WSWZ  = 184320;                    // 2MB
  const size_t OFF_WOUT  = OFF_WSWZ  + 2097152;       // 512KB
  const size_t OFF_HX    = OFF_WOUT  + 524288;        // 256KB tagged h exchange
  const size_t OFF_HSB   = OFF_HX    + 262144;        // 32MB
  const size_t OFF_ZXA   = OFF_HSB   + 33554432;      // 16MB
  const size_t OFF_ZYB   = OFF_ZXA   + 16777216;      // 16MB
  const size_t OFF_THD   = OFF_ZYB   + 16777216;      // 33.5MB bf16 theta diag
  const size_t OFF_ZMEAN = OFF_THD   + 33521664;      // 128KB f32 col-sums
  const size_t OFF_AOUT  = OFF_ZMEAN + 131072;        // 128B
  float* table = (float*)(ws + OFF_TABLE);
  unsigned short* Wswz    = (unsigned short*)(ws + OFF_WSWZ);
  unsigned short* woutswz = (unsigned short*)(ws + OFF_WOUT);
  unsigned* hx = (unsigned*)(ws + OFF_HX);
  unsigned short* hsb  = (unsigned short*)(ws + OFF_HSB);
  unsigned short* zxA  = (unsigned short*)(ws + OFF_ZXA);
  unsigned short* zyB  = (unsigned short*)(ws + OFF_ZYB);
  unsigned short* thD  = (unsigned short*)(ws + OFF_THD);
  float* zmean = (float*)(ws + OFF_ZMEAN);
  float* Aout  = (float*)(ws + OFF_AOUT);

  hipMemsetAsync(hx, 0, 262144, stream);     // tags/data = 0 each launch (graph replay)
  hipMemsetAsync(zmean, 0, 131072, stream);  // column-sum accumulators

  table_k<<<dim3(8,22), 256, 0, stream>>>(emb, W_ih, b_lstm, table);
  wprep_k<<<2048, 64, 0, stream>>>(W_hh, Wswz);
  wprep2_k<<<512, 64, 0, stream>>>(W_out, woutswz);
  lstm_wave<<<128, 64, 0, stream>>>(x, y, table, Wswz, hx, hsb);
  zproj_mfma<<<dim3(256,4), 256, 0, stream>>>(hsb, woutswz, b_out, zxA, zyB, zmean);
  theta_diag_k<<<dim3(4,4,32), 256, 0, stream>>>(zxA, zyB, thD);
  gap_k<<<32, 256, 0, stream>>>(zmean, b_out, W_gap, b_gap, Aout);
  nw_k<<<32, 64, 0, stream>>>(thD, Aout, out);
}